// Round 1
// baseline (866.839 us; speedup 1.0000x reference)
//
#include <hip/hip_runtime.h>
#include <math.h>

#define HID 32
#define NFEAT 100
#define WLDA 101   // 101 is odd -> h*101 % 32 is a bijection over lanes: conflict-free LDS reads

// Kernel 1: x = relu(X @ w1^T + b1); xn = x / max(||x||,1e-12);
// initialize denom[i] = exp(beta * <xn_i, xn_i>) (self-loop) and acc[i] = denom[i] * x[i].
__global__ __launch_bounds__(256) void k1_lin1_norm(
    const float* __restrict__ X, const float* __restrict__ w1,
    const float* __restrict__ b1, const float* __restrict__ pbeta,
    float* __restrict__ x, float* __restrict__ xn,
    float* __restrict__ acc, float* __restrict__ denom, int N)
{
    __shared__ float wl[HID * WLDA];
    __shared__ float xs[8 * NFEAT];
    const int tid = threadIdx.x;
    for (int i = tid; i < HID * NFEAT; i += 256)
        wl[(i / NFEAT) * WLDA + (i % NFEAT)] = w1[i];
    const int n0 = blockIdx.x * 8;
    for (int i = tid; i < 8 * NFEAT; i += 256) {
        int node = n0 + i / NFEAT;
        xs[i] = (node < N) ? X[(size_t)node * NFEAT + (i % NFEAT)] : 0.f;
    }
    __syncthreads();

    const int local = tid >> 5;   // node within block: 0..7
    const int h     = tid & 31;   // hidden unit: 0..31
    const int node  = n0 + local;
    if (node >= N) return;

    const float* xr = xs + local * NFEAT;
    const float* wr = wl + h * WLDA;
    float d = 0.f;
    #pragma unroll
    for (int k = 0; k < NFEAT; ++k) d = fmaf(xr[k], wr[k], d);

    float v = fmaxf(d + b1[h], 0.f);          // relu(lin1)
    float s = v * v;
    #pragma unroll
    for (int m = 16; m >= 1; m >>= 1) s += __shfl_xor(s, m, 32);
    float inv = 1.f / fmaxf(sqrtf(s), 1e-12f);
    float vn = v * inv;
    float selfdot = s * inv * inv;            // == <xn,xn>
    float beta = *pbeta;
    float eself = expf(beta * selfdot);

    size_t base = (size_t)node * HID + h;
    x[base]  = v;
    xn[base] = vn;
    acc[base] = eself * v;                    // self-loop contribution
    if (h == 0) denom[node] = eself;
}

// Kernel 2: per edge e: d = <xn[tgt], xn[src]>, w = exp(beta*d);
// denom[tgt] += w; acc[tgt][:] += w * x[src][:].  8 lanes per edge.
__global__ __launch_bounds__(256) void k2_edges(
    const int* __restrict__ ei, const float* __restrict__ x,
    const float* __restrict__ xn, const float* __restrict__ pbeta,
    float* __restrict__ acc, float* __restrict__ denom, int E)
{
    const int edge = blockIdx.x * 32 + (threadIdx.x >> 3);
    const int g    = threadIdx.x & 7;
    if (edge >= E) return;
    const int s_ = ei[edge];       // src j
    const int t_ = ei[E + edge];   // tgt i
    const float4 a = *(const float4*)(xn + (size_t)t_ * HID + g * 4);
    const float4 b = *(const float4*)(xn + (size_t)s_ * HID + g * 4);
    float p = a.x * b.x + a.y * b.y + a.z * b.z + a.w * b.w;
    p += __shfl_xor(p, 1, 8);
    p += __shfl_xor(p, 2, 8);
    p += __shfl_xor(p, 4, 8);
    const float e = expf((*pbeta) * p);   // no max-shift: |beta*p| <= |beta|, exp safe
    if (g == 0) atomicAdd(denom + t_, e);
    const float4 xsv = *(const float4*)(x + (size_t)s_ * HID + g * 4);
    float* ap = acc + (size_t)t_ * HID + g * 4;
    atomicAdd(ap + 0, e * xsv.x);
    atomicAdd(ap + 1, e * xsv.y);
    atomicAdd(ap + 2, e * xsv.z);
    atomicAdd(ap + 3, e * xsv.w);
}

// Kernel 3: out_row = acc[i]/denom[i]; logits = lin2(out_row); log_softmax.
__global__ __launch_bounds__(256) void k3_out(
    const float* __restrict__ acc, const float* __restrict__ denom,
    const float* __restrict__ w2, const float* __restrict__ b2,
    float* __restrict__ out, int N)
{
    __shared__ float w[2 * HID];
    __shared__ float b[2];
    if (threadIdx.x < 2 * HID) w[threadIdx.x] = w2[threadIdx.x];
    if (threadIdx.x < 2) b[threadIdx.x] = b2[threadIdx.x];
    __syncthreads();
    const int i = blockIdx.x * 256 + threadIdx.x;
    if (i >= N) return;
    const float invd = 1.f / denom[i];
    float l0 = b[0], l1 = b[1];
    const float* ar = acc + (size_t)i * HID;
    #pragma unroll
    for (int h = 0; h < HID; ++h) {
        float o = ar[h] * invd;
        l0 = fmaf(o, w[h], l0);
        l1 = fmaf(o, w[HID + h], l1);
    }
    float m = fmaxf(l0, l1);
    float lse = m + logf(expf(l0 - m) + expf(l1 - m));
    out[2 * i]     = l0 - lse;
    out[2 * i + 1] = l1 - lse;
}

extern "C" void kernel_launch(void* const* d_in, const int* in_sizes, int n_in,
                              void* d_out, int out_size, void* d_ws, size_t ws_size,
                              hipStream_t stream) {
    const float* X     = (const float*)d_in[0];
    const float* w1    = (const float*)d_in[1];
    const float* b1    = (const float*)d_in[2];
    const float* beta  = (const float*)d_in[3];
    const float* w2    = (const float*)d_in[4];
    const float* b2    = (const float*)d_in[5];
    const int*   ei    = (const int*)d_in[6];

    const int N = in_sizes[0] / NFEAT;      // 100000
    const int E = in_sizes[6] / 2;          // 1600000
    float* ws    = (float*)d_ws;
    float* x     = ws;                       // [N,32]
    float* xn    = ws + (size_t)N * HID;     // [N,32]
    float* acc   = ws + 2 * (size_t)N * HID; // [N,32]
    float* denom = ws + 3 * (size_t)N * HID; // [N]
    float* out   = (float*)d_out;

    k1_lin1_norm<<<(N + 7) / 8, 256, 0, stream>>>(X, w1, b1, beta, x, xn, acc, denom, N);
    k2_edges<<<(E + 31) / 32, 256, 0, stream>>>(ei, x, xn, beta, acc, denom, E);
    k3_out<<<(N + 255) / 256, 256, 0, stream>>>(acc, denom, w2, b2, out, N);
}

// Round 2
// 393.076 us; speedup vs baseline: 2.2053x; 2.2053x over previous
//
#include <hip/hip_runtime.h>
#include <math.h>

#define HID 32
#define NFEAT 100
#define WLDA 101   // odd stride -> conflict-free LDS reads across 32 lanes

// ---------------- Kernel 1: x = relu(X@w1^T + b1); xn = x/max(||x||,1e-12) ----------------
__global__ __launch_bounds__(256) void k1_lin1_norm(
    const float* __restrict__ X, const float* __restrict__ w1,
    const float* __restrict__ b1,
    float* __restrict__ x, float* __restrict__ xn, int N)
{
    __shared__ float wl[HID * WLDA];
    __shared__ float xs[8 * NFEAT];
    const int tid = threadIdx.x;
    for (int i = tid; i < HID * NFEAT; i += 256)
        wl[(i / NFEAT) * WLDA + (i % NFEAT)] = w1[i];
    const int n0 = blockIdx.x * 8;
    for (int i = tid; i < 8 * NFEAT; i += 256) {
        int node = n0 + i / NFEAT;
        xs[i] = (node < N) ? X[(size_t)node * NFEAT + (i % NFEAT)] : 0.f;
    }
    __syncthreads();

    const int local = tid >> 5;
    const int h     = tid & 31;
    const int node  = n0 + local;
    if (node >= N) return;

    const float* xr = xs + local * NFEAT;
    const float* wr = wl + h * WLDA;
    float d = 0.f;
    #pragma unroll
    for (int k = 0; k < NFEAT; ++k) d = fmaf(xr[k], wr[k], d);

    float v = fmaxf(d + b1[h], 0.f);
    float s = v * v;
    #pragma unroll
    for (int m = 16; m >= 1; m >>= 1) s += __shfl_xor(s, m, 32);
    float inv = 1.f / fmaxf(sqrtf(s), 1e-12f);

    size_t base = (size_t)node * HID + h;
    x[base]  = v;
    xn[base] = v * inv;
}

// ---------------- Counting sort of edges by target ----------------
__global__ __launch_bounds__(256) void k_hist(const int* __restrict__ ei, int* __restrict__ deg, int E) {
    int e = blockIdx.x * 256 + threadIdx.x;
    if (e < E) atomicAdd(&deg[ei[E + e]], 1);
}

// Block-level exclusive scan over 1024 elements; per-block total to bsum.
__global__ __launch_bounds__(1024) void k_scan1(const int* __restrict__ deg, int* __restrict__ off,
                                                int* __restrict__ bsum, int N) {
    __shared__ int wsum[16];
    int i = blockIdx.x * 1024 + threadIdx.x;
    int v = (i < N) ? deg[i] : 0;
    int xv = v;
    #pragma unroll
    for (int d = 1; d < 64; d <<= 1) {
        int y = __shfl_up(xv, d, 64);
        if ((threadIdx.x & 63) >= d) xv += y;
    }
    int wid = threadIdx.x >> 6;
    if ((threadIdx.x & 63) == 63) wsum[wid] = xv;
    __syncthreads();
    if (threadIdx.x < 16) {
        int s = wsum[threadIdx.x];
        #pragma unroll
        for (int d = 1; d < 16; d <<= 1) {
            int y = __shfl_up(s, d, 64);
            if ((int)threadIdx.x >= d) s += y;
        }
        wsum[threadIdx.x] = s;
    }
    __syncthreads();
    int base = (wid > 0) ? wsum[wid - 1] : 0;
    int incl = base + xv;
    if (i < N) off[i] = incl - v;
    if (threadIdx.x == 1023) bsum[blockIdx.x] = incl;
}

// Serial exclusive scan of the (<=128) block sums, done in LDS by one thread.
__global__ __launch_bounds__(128) void k_scan2(int* __restrict__ bsum, int B) {
    __shared__ int s[128];
    if (threadIdx.x < B) s[threadIdx.x] = bsum[threadIdx.x];
    __syncthreads();
    if (threadIdx.x == 0) {
        int run = 0;
        for (int i = 0; i < B; ++i) { int t = s[i]; s[i] = run; run += t; }
    }
    __syncthreads();
    if (threadIdx.x < B) bsum[threadIdx.x] = s[threadIdx.x];
}

__global__ __launch_bounds__(256) void k_scan_add(int* __restrict__ off, int* __restrict__ cursor,
                                                  const int* __restrict__ bsum, int N) {
    int i = blockIdx.x * 256 + threadIdx.x;
    if (i < N) {
        int o = off[i] + bsum[i >> 10];
        off[i] = o;
        cursor[i] = o;
    }
}

__global__ __launch_bounds__(256) void k_scatter(const int* __restrict__ ei, int* __restrict__ cursor,
                                                  int* __restrict__ sorted, int E) {
    int e = blockIdx.x * 256 + threadIdx.x;
    if (e < E) {
        int t = ei[E + e];
        int pos = atomicAdd(&cursor[t], 1);
        sorted[pos] = ei[e];
    }
}

// ---------------- Gather + softmax-weighted sum + lin2 + log_softmax ----------------
// One wave (64 lanes) per target node: 8 edge slots x 8 feature-lanes (float4 each).
__global__ __launch_bounds__(256) void k_gather(
    const int* __restrict__ sorted, const int* __restrict__ off, const int* __restrict__ deg,
    const float* __restrict__ x, const float* __restrict__ xn, const float* __restrict__ pbeta,
    const float* __restrict__ w2, const float* __restrict__ b2,
    float* __restrict__ out, int N)
{
    const int lane = threadIdx.x & 63;
    const int i = blockIdx.x * 4 + (threadIdx.x >> 6);
    if (i >= N) return;
    const int g   = lane & 7;   // feature slice: floats g*4 .. g*4+3
    const int sub = lane >> 3;  // edge slot 0..7
    const float beta = *pbeta;

    const float4 xnt = *(const float4*)(xn + (size_t)i * HID + g * 4);
    float sd = xnt.x * xnt.x + xnt.y * xnt.y + xnt.z * xnt.z + xnt.w * xnt.w;
    sd += __shfl_xor(sd, 1, 64); sd += __shfl_xor(sd, 2, 64); sd += __shfl_xor(sd, 4, 64);

    float a0 = 0.f, a1 = 0.f, a2 = 0.f, a3 = 0.f, dsum = 0.f;
    const int start = off[i];
    const int d = deg[i];
    for (int base = 0; base < d; base += 8) {
        const int e = base + sub;
        if (e < d) {  // uniform within each 8-lane group (same sub)
            const int s_ = sorted[start + e];
            const float4 xns = *(const float4*)(xn + (size_t)s_ * HID + g * 4);
            float p = xnt.x * xns.x + xnt.y * xns.y + xnt.z * xns.z + xnt.w * xns.w;
            p += __shfl_xor(p, 1, 64); p += __shfl_xor(p, 2, 64); p += __shfl_xor(p, 4, 64);
            const float w = expf(beta * p);   // |beta*p| <= |beta|: no max-shift needed
            const float4 xs = *(const float4*)(x + (size_t)s_ * HID + g * 4);
            a0 += w * xs.x; a1 += w * xs.y; a2 += w * xs.z; a3 += w * xs.w;
            dsum += w;
        }
    }
    // combine the 8 edge slots (all lanes end with full sums)
    #pragma unroll
    for (int m = 8; m <= 32; m <<= 1) {
        a0 += __shfl_xor(a0, m, 64); a1 += __shfl_xor(a1, m, 64);
        a2 += __shfl_xor(a2, m, 64); a3 += __shfl_xor(a3, m, 64);
        dsum += __shfl_xor(dsum, m, 64);
    }
    // self-loop
    const float wself = expf(beta * sd);
    const float4 xt = *(const float4*)(x + (size_t)i * HID + g * 4);
    a0 += wself * xt.x; a1 += wself * xt.y; a2 += wself * xt.z; a3 += wself * xt.w;
    dsum += wself;

    const float invd = 1.f / dsum;
    const float o0 = a0 * invd, o1 = a1 * invd, o2 = a2 * invd, o3 = a3 * invd;
    // logits: lane g covers features g*4..g*4+3
    float l0 = o0 * w2[g * 4] + o1 * w2[g * 4 + 1] + o2 * w2[g * 4 + 2] + o3 * w2[g * 4 + 3];
    float l1 = o0 * w2[HID + g * 4] + o1 * w2[HID + g * 4 + 1]
             + o2 * w2[HID + g * 4 + 2] + o3 * w2[HID + g * 4 + 3];
    l0 += __shfl_xor(l0, 1, 64); l0 += __shfl_xor(l0, 2, 64); l0 += __shfl_xor(l0, 4, 64);
    l1 += __shfl_xor(l1, 1, 64); l1 += __shfl_xor(l1, 2, 64); l1 += __shfl_xor(l1, 4, 64);
    if (lane == 0) {
        l0 += b2[0]; l1 += b2[1];
        float m = fmaxf(l0, l1);
        float lse = m + logf(expf(l0 - m) + expf(l1 - m));
        out[2 * (size_t)i]     = l0 - lse;
        out[2 * (size_t)i + 1] = l1 - lse;
    }
}

extern "C" void kernel_launch(void* const* d_in, const int* in_sizes, int n_in,
                              void* d_out, int out_size, void* d_ws, size_t ws_size,
                              hipStream_t stream) {
    const float* X    = (const float*)d_in[0];
    const float* w1   = (const float*)d_in[1];
    const float* b1   = (const float*)d_in[2];
    const float* beta = (const float*)d_in[3];
    const float* w2   = (const float*)d_in[4];
    const float* b2   = (const float*)d_in[5];
    const int*   ei   = (const int*)d_in[6];

    const int N = in_sizes[0] / NFEAT;   // 100000
    const int E = in_sizes[6] / 2;       // 1600000

    char* wsb = (char*)d_ws;
    float* x      = (float*)wsb;                      wsb += (size_t)N * HID * 4;
    float* xn     = (float*)wsb;                      wsb += (size_t)N * HID * 4;
    int*   deg    = (int*)wsb;                        wsb += (size_t)N * 4;
    int*   off    = (int*)wsb;                        wsb += (size_t)N * 4;
    int*   cursor = (int*)wsb;                        wsb += (size_t)N * 4;
    int*   bsum   = (int*)wsb;                        wsb += 256 * 4;
    int*   sorted = (int*)wsb;                        wsb += (size_t)E * 4;
    float* out    = (float*)d_out;

    const int B = (N + 1023) / 1024;   // scan blocks (98)

    hipMemsetAsync(deg, 0, (size_t)N * sizeof(int), stream);
    k1_lin1_norm<<<(N + 7) / 8, 256, 0, stream>>>(X, w1, b1, x, xn, N);
    k_hist<<<(E + 255) / 256, 256, 0, stream>>>(ei, deg, E);
    k_scan1<<<B, 1024, 0, stream>>>(deg, off, bsum, N);
    k_scan2<<<1, 128, 0, stream>>>(bsum, B);
    k_scan_add<<<(N + 255) / 256, 256, 0, stream>>>(off, cursor, bsum, N);
    k_scatter<<<(E + 255) / 256, 256, 0, stream>>>(ei, cursor, sorted, E);
    k_gather<<<(N + 3) / 4, 256, 0, stream>>>(sorted, off, deg, x, xn, beta, w2, b2, out, N);
}

// Round 3
// 272.764 us; speedup vs baseline: 3.1780x; 1.4411x over previous
//
#include <hip/hip_runtime.h>
#include <math.h>

#define HID 32
#define NFEAT 100
#define WLDA 101     // odd stride -> conflict-free LDS reads across 32 lanes
#define MAXNB 2048   // max target buckets (N/64); N=100k -> 1563
#define EPB 8192     // edges per block in hist/bin passes

// ---------------- Kernel 1: xn = normalize(relu(X@w1^T + b1)); sv = ||row|| ----------------
__global__ __launch_bounds__(256) void k1_lin1_norm(
    const float* __restrict__ X, const float* __restrict__ w1,
    const float* __restrict__ b1,
    float* __restrict__ xn, float* __restrict__ sv, int N)
{
    __shared__ float wl[HID * WLDA];
    __shared__ float xs[8 * NFEAT];
    const int tid = threadIdx.x;
    for (int i = tid; i < HID * NFEAT; i += 256)
        wl[(i / NFEAT) * WLDA + (i % NFEAT)] = w1[i];
    const int n0 = blockIdx.x * 8;
    for (int i = tid; i < 8 * NFEAT; i += 256) {
        int node = n0 + i / NFEAT;
        xs[i] = (node < N) ? X[(size_t)node * NFEAT + (i % NFEAT)] : 0.f;
    }
    __syncthreads();

    const int local = tid >> 5;
    const int h     = tid & 31;
    const int node  = n0 + local;
    if (node >= N) return;

    const float* xr = xs + local * NFEAT;
    const float* wr = wl + h * WLDA;
    float d = 0.f;
    #pragma unroll
    for (int k = 0; k < NFEAT; ++k) d = fmaf(xr[k], wr[k], d);

    float v = fmaxf(d + b1[h], 0.f);
    float s = v * v;
    #pragma unroll
    for (int m = 16; m >= 1; m >>= 1) s += __shfl_xor(s, m, 32);
    float norm = sqrtf(s);
    float inv = 1.f / fmaxf(norm, 1e-12f);

    xn[(size_t)node * HID + h] = v * inv;
    if (h == 0) sv[node] = norm;   // x = norm * xn exactly (v==0 when norm<eps)
}

// ---------------- Bucket histogram (bucket = tgt >> 6), LDS-aggregated ----------------
__global__ __launch_bounds__(256) void kb_hist(const int* __restrict__ ei,
                                               int* __restrict__ bcnt, int E, int NB)
{
    __shared__ int h[MAXNB];
    const int tid = threadIdx.x;
    for (int i = tid; i < NB; i += 256) h[i] = 0;
    __syncthreads();
    const int start = blockIdx.x * EPB;
    const int end = min(start + EPB, E);
    for (int e = start + tid; e < end; e += 256)
        atomicAdd(&h[ei[E + e] >> 6], 1);
    __syncthreads();
    for (int i = tid; i < NB; i += 256)
        if (h[i]) atomicAdd(&bcnt[i], h[i]);
}

// ---------------- Exclusive scan of bucket counts (single block) ----------------
__global__ __launch_bounds__(256) void kb_scan(const int* __restrict__ bcnt,
                                               int* __restrict__ boff,
                                               int* __restrict__ bcur, int NB)
{
    __shared__ int s[MAXNB + 1];
    const int tid = threadIdx.x;
    for (int i = tid; i < NB; i += 256) s[i] = bcnt[i];
    __syncthreads();
    if (tid == 0) {
        int run = 0;
        for (int i = 0; i < NB; ++i) { int t = s[i]; s[i] = run; run += t; }
        s[NB] = run;
    }
    __syncthreads();
    for (int i = tid; i <= NB; i += 256) boff[i] = s[i];
    for (int i = tid; i < NB; i += 256) bcur[i] = s[i];
}

// ---------------- Bin edges into bucket regions: binned[pos] = src | (local<<17) ----------------
__global__ __launch_bounds__(256) void kb_bin(const int* __restrict__ ei,
                                              int* __restrict__ bcur,
                                              int* __restrict__ binned, int E, int NB)
{
    __shared__ int h[MAXNB];
    __shared__ int base[MAXNB];
    const int tid = threadIdx.x;
    for (int i = tid; i < NB; i += 256) h[i] = 0;
    __syncthreads();
    const int start = blockIdx.x * EPB;
    const int end = min(start + EPB, E);
    for (int e = start + tid; e < end; e += 256)
        atomicAdd(&h[ei[E + e] >> 6], 1);
    __syncthreads();
    for (int i = tid; i < NB; i += 256) {
        int c = h[i];
        base[i] = c ? atomicAdd(&bcur[i], c) : 0;
    }
    __syncthreads();
    for (int i = tid; i < NB; i += 256) h[i] = 0;   // reuse as local cursor
    __syncthreads();
    for (int e = start + tid; e < end; e += 256) {
        int t = ei[E + e];
        int b = t >> 6;
        int r = atomicAdd(&h[b], 1);
        binned[base[b] + r] = ei[e] | ((t & 63) << 17);
    }
}

// ---------------- Per-bucket: local degrees -> CSR off/deg, scatter {src, s} ----------------
__global__ __launch_bounds__(256) void kc_sort(
    const int* __restrict__ binned, const int* __restrict__ boff,
    const float* __restrict__ sv, int2* __restrict__ sorted8,
    int* __restrict__ off, int* __restrict__ deg, int N)
{
    __shared__ int cnt[64];
    __shared__ int cur[64];
    const int tid = threadIdx.x;
    const int b = blockIdx.x;
    if (tid < 64) cnt[tid] = 0;
    __syncthreads();
    const int s0 = boff[b], s1 = boff[b + 1];
    for (int i = s0 + tid; i < s1; i += 256)
        atomicAdd(&cnt[binned[i] >> 17], 1);
    __syncthreads();
    if (tid < 64) {   // wave 0: exclusive scan of 64 counts
        int c = cnt[tid];
        int x = c;
        #pragma unroll
        for (int d = 1; d < 64; d <<= 1) {
            int y = __shfl_up(x, d, 64);
            if (tid >= d) x += y;
        }
        int start = s0 + x - c;
        int node = b * 64 + tid;
        if (node < N) { off[node] = start; deg[node] = c; }
        cur[tid] = start;
    }
    __syncthreads();
    for (int i = s0 + tid; i < s1; i += 256) {
        int w = binned[i];
        int src = w & 0x1FFFF;
        int pos = atomicAdd(&cur[w >> 17], 1);
        sorted8[pos] = make_int2(src, __float_as_int(sv[src]));
    }
}

// ---------------- Gather: softmax-weighted mean + lin2 + log_softmax ----------------
// One wave per target node: 8 edge slots x 8 feature-lanes (float4 each).
__global__ __launch_bounds__(256) void k_gather(
    const int2* __restrict__ sorted8, const int* __restrict__ off, const int* __restrict__ deg,
    const float* __restrict__ xn, const float* __restrict__ sv, const float* __restrict__ pbeta,
    const float* __restrict__ w2, const float* __restrict__ b2,
    float* __restrict__ out, int N)
{
    const int lane = threadIdx.x & 63;
    const int i = blockIdx.x * 4 + (threadIdx.x >> 6);
    if (i >= N) return;
    const int g   = lane & 7;   // feature slice: floats g*4 .. g*4+3
    const int sub = lane >> 3;  // edge slot 0..7
    const float beta = *pbeta;

    const float4 xnt = *(const float4*)(xn + (size_t)i * HID + g * 4);
    float sd = xnt.x * xnt.x + xnt.y * xnt.y + xnt.z * xnt.z + xnt.w * xnt.w;
    sd += __shfl_xor(sd, 1, 64); sd += __shfl_xor(sd, 2, 64); sd += __shfl_xor(sd, 4, 64);

    float a0 = 0.f, a1 = 0.f, a2 = 0.f, a3 = 0.f, dsum = 0.f;
    const int start = off[i];
    const int d = deg[i];
    for (int base = 0; base < d; base += 8) {
        const int e = base + sub;
        if (e < d) {  // uniform within each 8-lane group
            const int2 ent = sorted8[start + e];
            const int s_ = ent.x;
            const float4 xns = *(const float4*)(xn + (size_t)s_ * HID + g * 4);
            float p = xnt.x * xns.x + xnt.y * xns.y + xnt.z * xns.z + xnt.w * xns.w;
            p += __shfl_xor(p, 1, 64); p += __shfl_xor(p, 2, 64); p += __shfl_xor(p, 4, 64);
            const float w = expf(beta * p);          // |beta*p| <= |beta|: safe
            const float f = w * __int_as_float(ent.y);  // w * ||x_src||
            a0 += f * xns.x; a1 += f * xns.y; a2 += f * xns.z; a3 += f * xns.w;
            dsum += w;
        }
    }
    #pragma unroll
    for (int m = 8; m <= 32; m <<= 1) {
        a0 += __shfl_xor(a0, m, 64); a1 += __shfl_xor(a1, m, 64);
        a2 += __shfl_xor(a2, m, 64); a3 += __shfl_xor(a3, m, 64);
        dsum += __shfl_xor(dsum, m, 64);
    }
    // self-loop: x_i = sv[i] * xn_i
    const float wself = expf(beta * sd);
    const float fs = wself * sv[i];
    a0 += fs * xnt.x; a1 += fs * xnt.y; a2 += fs * xnt.z; a3 += fs * xnt.w;
    dsum += wself;

    const float invd = 1.f / dsum;
    const float o0 = a0 * invd, o1 = a1 * invd, o2 = a2 * invd, o3 = a3 * invd;
    float l0 = o0 * w2[g * 4] + o1 * w2[g * 4 + 1] + o2 * w2[g * 4 + 2] + o3 * w2[g * 4 + 3];
    float l1 = o0 * w2[HID + g * 4] + o1 * w2[HID + g * 4 + 1]
             + o2 * w2[HID + g * 4 + 2] + o3 * w2[HID + g * 4 + 3];
    l0 += __shfl_xor(l0, 1, 64); l0 += __shfl_xor(l0, 2, 64); l0 += __shfl_xor(l0, 4, 64);
    l1 += __shfl_xor(l1, 1, 64); l1 += __shfl_xor(l1, 2, 64); l1 += __shfl_xor(l1, 4, 64);
    if (lane == 0) {
        l0 += b2[0]; l1 += b2[1];
        float m = fmaxf(l0, l1);
        float lse = m + logf(expf(l0 - m) + expf(l1 - m));
        out[2 * (size_t)i]     = l0 - lse;
        out[2 * (size_t)i + 1] = l1 - lse;
    }
}

extern "C" void kernel_launch(void* const* d_in, const int* in_sizes, int n_in,
                              void* d_out, int out_size, void* d_ws, size_t ws_size,
                              hipStream_t stream) {
    const float* X    = (const float*)d_in[0];
    const float* w1   = (const float*)d_in[1];
    const float* b1   = (const float*)d_in[2];
    const float* beta = (const float*)d_in[3];
    const float* w2   = (const float*)d_in[4];
    const float* b2   = (const float*)d_in[5];
    const int*   ei   = (const int*)d_in[6];

    const int N = in_sizes[0] / NFEAT;   // 100000
    const int E = in_sizes[6] / 2;       // 1600000
    const int NB = (N + 63) >> 6;        // 1563 target buckets

    char* wsb = (char*)d_ws;
    float* xn      = (float*)wsb;  wsb += (size_t)N * HID * 4;      // 12.8 MB
    int2*  sorted8 = (int2*)wsb;   wsb += (size_t)E * 8;            // 12.8 MB
    int*   binned  = (int*)wsb;    wsb += (size_t)E * 4;            //  6.4 MB
    float* sv      = (float*)wsb;  wsb += (size_t)N * 4;
    int*   off     = (int*)wsb;    wsb += (size_t)N * 4;
    int*   deg     = (int*)wsb;    wsb += (size_t)N * 4;
    int*   bcnt    = (int*)wsb;    wsb += (size_t)(MAXNB + 8) * 4;
    int*   boff    = (int*)wsb;    wsb += (size_t)(MAXNB + 8) * 4;
    int*   bcur    = (int*)wsb;    wsb += (size_t)(MAXNB + 8) * 4;
    float* out     = (float*)d_out;

    const int EB = (E + EPB - 1) / EPB;   // 196 blocks for hist/bin

    hipMemsetAsync(bcnt, 0, (size_t)NB * sizeof(int), stream);
    k1_lin1_norm<<<(N + 7) / 8, 256, 0, stream>>>(X, w1, b1, xn, sv, N);
    kb_hist<<<EB, 256, 0, stream>>>(ei, bcnt, E, NB);
    kb_scan<<<1, 256, 0, stream>>>(bcnt, boff, bcur, NB);
    kb_bin<<<EB, 256, 0, stream>>>(ei, bcur, binned, E, NB);
    kc_sort<<<NB, 256, 0, stream>>>(binned, boff, sv, sorted8, off, deg, N);
    k_gather<<<(N + 3) / 4, 256, 0, stream>>>(sorted8, off, deg, xn, sv, beta, w2, b2, out, N);
}

// Round 4
// 265.356 us; speedup vs baseline: 3.2667x; 1.0279x over previous
//
#include <hip/hip_runtime.h>
#include <math.h>

#define HID 32
#define NFEAT 100
#define WLDA 101     // odd stride -> conflict-free LDS reads across 32 lanes
#define MAXNB 2048   // max target buckets (N/64); N=100k -> 1563
#define EPB 16384    // edges per block in hist/bin passes
#define CAP 3072     // LDS edge capacity per bucket in k_fused (avg 1024, P(>2048)~e^-300)

// ---------------- Kernel 1: xn = normalize(relu(X@w1^T + b1)); sv = ||row|| ----------------
__global__ __launch_bounds__(256) void k1_lin1_norm(
    const float* __restrict__ X, const float* __restrict__ w1,
    const float* __restrict__ b1,
    float* __restrict__ xn, float* __restrict__ sv, int N)
{
    __shared__ float wl[HID * WLDA];
    __shared__ float xs[8 * NFEAT];
    const int tid = threadIdx.x;
    for (int i = tid; i < HID * NFEAT; i += 256)
        wl[(i / NFEAT) * WLDA + (i % NFEAT)] = w1[i];
    const int n0 = blockIdx.x * 8;
    for (int i = tid; i < 8 * NFEAT; i += 256) {
        int node = n0 + i / NFEAT;
        xs[i] = (node < N) ? X[(size_t)node * NFEAT + (i % NFEAT)] : 0.f;
    }
    __syncthreads();

    const int local = tid >> 5;
    const int h     = tid & 31;
    const int node  = n0 + local;
    if (node >= N) return;

    const float* xr = xs + local * NFEAT;
    const float* wr = wl + h * WLDA;
    float d = 0.f;
    #pragma unroll
    for (int k = 0; k < NFEAT; ++k) d = fmaf(xr[k], wr[k], d);

    float v = fmaxf(d + b1[h], 0.f);
    float s = v * v;
    #pragma unroll
    for (int m = 16; m >= 1; m >>= 1) s += __shfl_xor(s, m, 32);
    float norm = sqrtf(s);
    float inv = 1.f / fmaxf(norm, 1e-12f);

    xn[(size_t)node * HID + h] = v * inv;
    if (h == 0) sv[node] = norm;   // x = norm * xn exactly (v==0 when norm<eps)
}

// ---------------- Bucket histogram (bucket = tgt >> 6), LDS-aggregated ----------------
__global__ __launch_bounds__(256) void kb_hist(const int* __restrict__ ei,
                                               int* __restrict__ bcnt, int E, int NB)
{
    __shared__ int h[MAXNB];
    const int tid = threadIdx.x;
    for (int i = tid; i < NB; i += 256) h[i] = 0;
    __syncthreads();
    const int start = blockIdx.x * EPB;
    const int end = min(start + EPB, E);
    for (int e = start + tid; e < end; e += 256)
        atomicAdd(&h[ei[E + e] >> 6], 1);
    __syncthreads();
    for (int i = tid; i < NB; i += 256)
        if (h[i]) atomicAdd(&bcnt[i], h[i]);
}

// ---------------- Parallel exclusive scan of bucket counts (single block) ----------------
__global__ __launch_bounds__(256) void kb_scan(const int* __restrict__ bcnt,
                                               int* __restrict__ boff,
                                               int* __restrict__ bcur, int NB, int E)
{
    __shared__ int wsum[4];
    __shared__ int carry_s;
    const int tid = threadIdx.x, lane = tid & 63, wid = tid >> 6;
    if (tid == 0) carry_s = 0;
    __syncthreads();
    const int nch = (NB + 255) / 256;
    for (int c = 0; c < nch; ++c) {
        int i = c * 256 + tid;
        int v = (i < NB) ? bcnt[i] : 0;
        int x = v;
        #pragma unroll
        for (int d = 1; d < 64; d <<= 1) {
            int y = __shfl_up(x, d, 64);
            if (lane >= d) x += y;
        }
        if (lane == 63) wsum[wid] = x;
        __syncthreads();
        int base = carry_s;
        if (wid > 0) base += wsum[0];
        if (wid > 1) base += wsum[1];
        if (wid > 2) base += wsum[2];
        int incl = base + x;
        if (i < NB) { boff[i] = incl - v; bcur[i] = incl - v; }
        __syncthreads();
        if (tid == 255) carry_s = incl;
        __syncthreads();
    }
    if (tid == 0) boff[NB] = E;
}

// ---------------- Bin edges into bucket regions: binned[pos] = src | (local<<17) ----------------
__global__ __launch_bounds__(256) void kb_bin(const int* __restrict__ ei,
                                              int* __restrict__ bcur,
                                              int* __restrict__ binned, int E, int NB)
{
    __shared__ int h[MAXNB];
    __shared__ int base[MAXNB];
    const int tid = threadIdx.x;
    for (int i = tid; i < NB; i += 256) h[i] = 0;
    __syncthreads();
    const int start = blockIdx.x * EPB;
    const int end = min(start + EPB, E);
    for (int e = start + tid; e < end; e += 256)
        atomicAdd(&h[ei[E + e] >> 6], 1);
    __syncthreads();
    for (int i = tid; i < NB; i += 256) {
        int c = h[i];
        base[i] = c ? atomicAdd(&bcur[i], c) : 0;
    }
    __syncthreads();
    for (int i = tid; i < NB; i += 256) h[i] = 0;   // reuse as local cursor
    __syncthreads();
    for (int e = start + tid; e < end; e += 256) {
        int t = ei[E + e];
        int b = t >> 6;
        int r = atomicAdd(&h[b], 1);
        binned[base[b] + r] = ei[e] | ((t & 63) << 17);
    }
}

// ---------------- Fused: per-bucket LDS sort + gather + lin2 + log_softmax ----------------
// Block = one bucket (64 target nodes). Sort bucket edges into LDS grouped by
// local target, then 4 waves x 16 nodes gather. One wave per node iteration:
// 8 edge slots x 8 feature-lanes (float4 each).
__global__ __launch_bounds__(256) void k_fused(
    const int* __restrict__ binned, const int* __restrict__ boff,
    const float* __restrict__ xn, const float* __restrict__ sv,
    const float* __restrict__ pbeta,
    const float* __restrict__ w2, const float* __restrict__ b2,
    float* __restrict__ out, int N)
{
    __shared__ int cnt[64];
    __shared__ int cur[64];
    __shared__ int led[CAP];
    const int tid  = threadIdx.x;
    const int lane = tid & 63;
    const int wv   = tid >> 6;
    const int g    = lane & 7;   // feature slice: floats g*4 .. g*4+3
    const int sub  = lane >> 3;  // edge slot 0..7
    const int b    = blockIdx.x;
    const int s0 = boff[b], s1 = boff[b + 1];
    const int sz = s1 - s0;
    const float beta = *pbeta;
    // per-lane lin2 weight slice (registers)
    const float w0a = w2[g*4], w0b = w2[g*4+1], w0c = w2[g*4+2], w0d = w2[g*4+3];
    const float w1a = w2[HID+g*4], w1b = w2[HID+g*4+1], w1c = w2[HID+g*4+2], w1d = w2[HID+g*4+3];
    const float bb0 = b2[0], bb1 = b2[1];

    if (tid < 64) cnt[tid] = 0;
    __syncthreads();
    for (int i = s0 + tid; i < s1; i += 256)
        atomicAdd(&cnt[binned[i] >> 17], 1);
    __syncthreads();
    if (tid < 64) {   // wave 0: exclusive scan of 64 counts -> local starts
        int c = cnt[tid];
        int x = c;
        #pragma unroll
        for (int d = 1; d < 64; d <<= 1) {
            int y = __shfl_up(x, d, 64);
            if (tid >= d) x += y;
        }
        cur[tid] = x - c;
    }
    __syncthreads();
    const bool fits = (sz <= CAP);
    if (fits) {
        for (int i = s0 + tid; i < s1; i += 256) {
            int w = binned[i];
            int pos = atomicAdd(&cur[w >> 17], 1);
            led[pos] = w & 0x1FFFF;
        }
    }
    __syncthreads();

    for (int local = wv; local < 64; local += 4) {
        const int node = b * 64 + local;
        if (node >= N) break;   // monotone -> uniform break

        const float4 xnt = *(const float4*)(xn + (size_t)node * HID + g * 4);
        float sd = xnt.x*xnt.x + xnt.y*xnt.y + xnt.z*xnt.z + xnt.w*xnt.w;
        sd += __shfl_xor(sd, 1, 64); sd += __shfl_xor(sd, 2, 64); sd += __shfl_xor(sd, 4, 64);

        float a0 = 0.f, a1 = 0.f, a2 = 0.f, a3 = 0.f, dsum = 0.f;
        const int deg = cnt[local];

        if (fits) {
            const int start = cur[local] - deg;   // cur ended at start+deg
            for (int e0 = 0; e0 < deg; e0 += 8) {
                const int e = e0 + sub;           // uniform within 8-lane group
                if (e < deg) {
                    const int s_ = led[start + e];
                    const float4 xns = *(const float4*)(xn + (size_t)s_ * HID + g * 4);
                    float p = xnt.x*xns.x + xnt.y*xns.y + xnt.z*xns.z + xnt.w*xns.w;
                    p += __shfl_xor(p, 1, 64); p += __shfl_xor(p, 2, 64); p += __shfl_xor(p, 4, 64);
                    const float wgt = __expf(beta * p);   // |beta*p| <= |beta|: safe
                    const float f = wgt * sv[s_];         // w * ||x_src||
                    a0 += f*xns.x; a1 += f*xns.y; a2 += f*xns.z; a3 += f*xns.w;
                    dsum += wgt;
                }
            }
        } else {
            // fallback (bucket overflow, practically never): scan range, filter by local id
            for (int j = s0; j < s1; j += 8) {
                const int e = j + sub;
                const int wrd = (e < s1) ? binned[e] : -1;
                const bool ok = (wrd >= 0) && ((wrd >> 17) == local);
                const int s_ = ok ? (wrd & 0x1FFFF) : 0;
                const float4 xns = *(const float4*)(xn + (size_t)s_ * HID + g * 4);
                float p = xnt.x*xns.x + xnt.y*xns.y + xnt.z*xns.z + xnt.w*xns.w;
                p += __shfl_xor(p, 1, 64); p += __shfl_xor(p, 2, 64); p += __shfl_xor(p, 4, 64);
                const float wgt = ok ? __expf(beta * p) : 0.f;
                const float f = wgt * sv[s_];
                a0 += f*xns.x; a1 += f*xns.y; a2 += f*xns.z; a3 += f*xns.w;
                dsum += wgt;
            }
        }
        // combine the 8 edge slots
        #pragma unroll
        for (int m = 8; m <= 32; m <<= 1) {
            a0 += __shfl_xor(a0, m, 64); a1 += __shfl_xor(a1, m, 64);
            a2 += __shfl_xor(a2, m, 64); a3 += __shfl_xor(a3, m, 64);
            dsum += __shfl_xor(dsum, m, 64);
        }
        // self-loop: x_i = sv[i] * xn_i
        const float wself = __expf(beta * sd);
        const float fs = wself * sv[node];
        a0 += fs*xnt.x; a1 += fs*xnt.y; a2 += fs*xnt.z; a3 += fs*xnt.w;
        dsum += wself;

        const float invd = 1.f / dsum;
        const float o0 = a0*invd, o1 = a1*invd, o2 = a2*invd, o3 = a3*invd;
        float l0 = o0*w0a + o1*w0b + o2*w0c + o3*w0d;
        float l1 = o0*w1a + o1*w1b + o2*w1c + o3*w1d;
        l0 += __shfl_xor(l0, 1, 64); l0 += __shfl_xor(l0, 2, 64); l0 += __shfl_xor(l0, 4, 64);
        l1 += __shfl_xor(l1, 1, 64); l1 += __shfl_xor(l1, 2, 64); l1 += __shfl_xor(l1, 4, 64);
        if (lane == 0) {
            l0 += bb0; l1 += bb1;
            float m = fmaxf(l0, l1);
            float lse = m + __logf(__expf(l0 - m) + __expf(l1 - m));
            out[2 * (size_t)node]     = l0 - lse;
            out[2 * (size_t)node + 1] = l1 - lse;
        }
    }
}

extern "C" void kernel_launch(void* const* d_in, const int* in_sizes, int n_in,
                              void* d_out, int out_size, void* d_ws, size_t ws_size,
                              hipStream_t stream) {
    const float* X    = (const float*)d_in[0];
    const float* w1   = (const float*)d_in[1];
    const float* b1   = (const float*)d_in[2];
    const float* beta = (const float*)d_in[3];
    const float* w2   = (const float*)d_in[4];
    const float* b2   = (const float*)d_in[5];
    const int*   ei   = (const int*)d_in[6];

    const int N = in_sizes[0] / NFEAT;   // 100000
    const int E = in_sizes[6] / 2;       // 1600000
    const int NB = (N + 63) >> 6;        // 1563 target buckets

    char* wsb = (char*)d_ws;
    float* xn     = (float*)wsb;  wsb += (size_t)N * HID * 4;      // 12.8 MB
    int*   binned = (int*)wsb;    wsb += (size_t)E * 4;            //  6.4 MB
    float* sv     = (float*)wsb;  wsb += (size_t)N * 4;
    int*   bcnt   = (int*)wsb;    wsb += (size_t)(MAXNB + 8) * 4;
    int*   boff   = (int*)wsb;    wsb += (size_t)(MAXNB + 8) * 4;
    int*   bcur   = (int*)wsb;    wsb += (size_t)(MAXNB + 8) * 4;
    float* out    = (float*)d_out;

    const int EB = (E + EPB - 1) / EPB;   // 98 blocks for hist/bin

    hipMemsetAsync(bcnt, 0, (size_t)NB * sizeof(int), stream);
    k1_lin1_norm<<<(N + 7) / 8, 256, 0, stream>>>(X, w1, b1, xn, sv, N);
    kb_hist<<<EB, 256, 0, stream>>>(ei, bcnt, E, NB);
    kb_scan<<<1, 256, 0, stream>>>(bcnt, boff, bcur, NB, E);
    kb_bin<<<EB, 256, 0, stream>>>(ei, bcur, binned, E, NB);
    k_fused<<<NB, 256, 0, stream>>>(binned, boff, xn, sv, beta, w2, b2, out, N);
}

// Round 5
// 226.856 us; speedup vs baseline: 3.8211x; 1.1697x over previous
//
#include <hip/hip_runtime.h>
#include <math.h>

#define HID 32
#define NFEAT 100
#define WLDA 101     // odd stride -> conflict-free LDS reads across 32 lanes
#define CHUNK 4096   // edges per chunk in kc_sort
#define NCMAX 512    // max chunks (E/CHUNK = 391)
#define NBMAX 2048   // max buckets (N/64 = 1563)
#define CAP 3072     // LDS edge capacity per bucket in k_fused (avg 1024)

// ---------------- Kernel 1: xn = normalize(relu(X@w1^T + b1)); sv = ||row|| ----------------
__global__ __launch_bounds__(256) void k1_lin1_norm(
    const float* __restrict__ X, const float* __restrict__ w1,
    const float* __restrict__ b1,
    float* __restrict__ xn, float* __restrict__ sv, int N)
{
    __shared__ float wl[HID * WLDA];
    __shared__ float4 xs4[8 * 25];
    float* xs = (float*)xs4;
    const int tid = threadIdx.x;
    const float4* w14 = (const float4*)w1;       // 32*100 floats = 800 float4
    for (int i = tid; i < 800; i += 256) {
        float4 v = w14[i];
        int r = i / 25, q = (i % 25) * 4;
        float* dst = wl + r * WLDA + q;
        dst[0] = v.x; dst[1] = v.y; dst[2] = v.z; dst[3] = v.w;
    }
    const int n0 = blockIdx.x * 8;
    const float4* X4 = (const float4*)X;         // row = 25 float4
    for (int i = tid; i < 200; i += 256) {
        int r = i / 25, q = i % 25;
        int node = n0 + r;
        xs4[i] = (node < N) ? X4[(size_t)node * 25 + q] : make_float4(0.f, 0.f, 0.f, 0.f);
    }
    __syncthreads();

    const int local = tid >> 5;
    const int h     = tid & 31;
    const int node  = n0 + local;
    if (node >= N) return;

    const float* xr = xs + local * NFEAT;
    const float* wr = wl + h * WLDA;
    float d = 0.f;
    #pragma unroll
    for (int k = 0; k < NFEAT; ++k) d = fmaf(xr[k], wr[k], d);

    float v = fmaxf(d + b1[h], 0.f);
    float s = v * v;
    #pragma unroll
    for (int m = 16; m >= 1; m >>= 1) s += __shfl_xor(s, m, 32);
    float norm = sqrtf(s);
    float inv = 1.f / fmaxf(norm, 1e-12f);

    xn[(size_t)node * HID + h] = v * inv;
    if (h == 0) sv[node] = norm;   // x = norm * xn exactly (v==0 when norm<eps)
}

// ---------------- Chunk-local bucket sort (no global atomics, no write amplification) --------
// Chunk c owns binned[c*CHUNK .. ), sorted by bucket (tgt>>6) within the chunk.
// off2dT[b*NC + c] = start of bucket b inside chunk c; row NB holds chunk edge counts.
__global__ __launch_bounds__(256) void kc_sort(
    const int* __restrict__ ei, int* __restrict__ binned,
    int* __restrict__ off2dT, int E, int NB, int NC)
{
    __shared__ int hist[NBMAX];
    __shared__ int off[NBMAX];
    const int tid = threadIdx.x;
    const int c = blockIdx.x;
    const int start = c * CHUNK;
    const int end = min(start + CHUNK, E);
    for (int b = tid; b < NB; b += 256) hist[b] = 0;
    __syncthreads();
    for (int e = start + tid; e < end; e += 256)
        atomicAdd(&hist[ei[E + e] >> 6], 1);
    __syncthreads();
    if (tid < 64) {   // wave 0: exclusive scan, 64 buckets per round with carry
        int carry = 0;
        for (int r = 0; r * 64 < NB; ++r) {
            int b = r * 64 + tid;
            int v = (b < NB) ? hist[b] : 0;
            int x = v;
            #pragma unroll
            for (int d = 1; d < 64; d <<= 1) {
                int y = __shfl_up(x, d, 64);
                if (tid >= d) x += y;
            }
            if (b < NB) off[b] = carry + x - v;
            carry += __shfl(x, 63, 64);
        }
    }
    __syncthreads();
    for (int b = tid; b < NB; b += 256) {
        off2dT[(size_t)b * NC + c] = off[b];
        hist[b] = off[b];             // reuse as local cursor
    }
    if (tid == 0) off2dT[(size_t)NB * NC + c] = end - start;
    __syncthreads();
    for (int e = start + tid; e < end; e += 256) {
        int t = ei[E + e];
        int b = t >> 6;
        int pos = atomicAdd(&hist[b], 1);
        binned[start + pos] = ei[e] | ((t & 63) << 17);  // src<2^17, local 6 bits
    }
}

// ---------------- Fused: collect sub-runs -> LDS sort by node -> gather + lin2 + lsm ---------
__global__ __launch_bounds__(256) void k_fused(
    const int* __restrict__ binned, const int* __restrict__ off2dT,
    const float* __restrict__ xn, const float* __restrict__ sv,
    const float* __restrict__ pbeta,
    const float* __restrict__ w2, const float* __restrict__ b2,
    float* __restrict__ out, int N, int NB, int NC)
{
    __shared__ int boff0[NCMAX], boff1[NCMAX];
    __shared__ int cnt[64], cur[64];
    __shared__ int led[CAP];
    __shared__ int ovf;
    const int tid  = threadIdx.x;
    const int lane = tid & 63;
    const int wv   = tid >> 6;
    const int g    = lane & 7;   // feature slice: floats g*4 .. g*4+3
    const int sub  = lane >> 3;  // edge slot 0..7
    const int b    = blockIdx.x;
    const float beta = *pbeta;
    const float w0a = w2[g*4], w0b = w2[g*4+1], w0c = w2[g*4+2], w0d = w2[g*4+3];
    const float w1a = w2[HID+g*4], w1b = w2[HID+g*4+1], w1c = w2[HID+g*4+2], w1d = w2[HID+g*4+3];
    const float bb0 = b2[0], bb1 = b2[1];

    for (int c = tid; c < NC; c += 256) {
        boff0[c] = off2dT[(size_t)b * NC + c];
        boff1[c] = off2dT[(size_t)(b + 1) * NC + c];
    }
    if (tid < 64) cnt[tid] = 0;
    if (tid == 0) ovf = 0;
    __syncthreads();
    // pass A: per-node degree counts
    for (int c = tid; c < NC; c += 256) {
        const int gbase = c * CHUNK;
        const int j1 = boff1[c];
        for (int j = boff0[c]; j < j1; ++j)
            atomicAdd(&cnt[binned[gbase + j] >> 17], 1);
    }
    __syncthreads();
    if (tid < 64) {
        int v = cnt[tid], x = v;
        #pragma unroll
        for (int d = 1; d < 64; d <<= 1) {
            int y = __shfl_up(x, d, 64);
            if (tid >= d) x += y;
        }
        cur[tid] = x - v;
        if (tid == 63 && x > CAP) ovf = 1;
    }
    __syncthreads();
    const bool fits = (ovf == 0);
    if (fits) {   // pass B: scatter into LDS grouped by local node
        for (int c = tid; c < NC; c += 256) {
            const int gbase = c * CHUNK;
            const int j1 = boff1[c];
            for (int j = boff0[c]; j < j1; ++j) {
                int w = binned[gbase + j];
                int pos = atomicAdd(&cur[w >> 17], 1);
                led[pos] = w & 0x1FFFF;
            }
        }
    }
    __syncthreads();

    for (int local = wv; local < 64; local += 4) {
        const int node = b * 64 + local;
        if (node >= N) break;   // monotone -> uniform break per wave

        const float4 xnt = *(const float4*)(xn + (size_t)node * HID + g * 4);
        float sd = xnt.x*xnt.x + xnt.y*xnt.y + xnt.z*xnt.z + xnt.w*xnt.w;
        sd += __shfl_xor(sd, 1, 64); sd += __shfl_xor(sd, 2, 64); sd += __shfl_xor(sd, 4, 64);

        float a0 = 0.f, a1 = 0.f, a2 = 0.f, a3 = 0.f, dsum = 0.f;
        const int deg = cnt[local];

        if (fits) {
            const int st = cur[local] - deg;   // cur ended at start+deg
            for (int e0 = 0; e0 < deg; e0 += 8) {
                const int e = e0 + sub;        // uniform within 8-lane group
                if (e < deg) {
                    const int s_ = led[st + e];
                    const float4 xns = *(const float4*)(xn + (size_t)s_ * HID + g * 4);
                    float p = xnt.x*xns.x + xnt.y*xns.y + xnt.z*xns.z + xnt.w*xns.w;
                    p += __shfl_xor(p, 1, 64); p += __shfl_xor(p, 2, 64); p += __shfl_xor(p, 4, 64);
                    const float wgt = __expf(beta * p);   // |beta*p| <= |beta|: safe
                    const float f = wgt * sv[s_];
                    a0 += f*xns.x; a1 += f*xns.y; a2 += f*xns.z; a3 += f*xns.w;
                    dsum += wgt;
                }
            }
        } else {
            // fallback (bucket > CAP, practically never): filter all sub-runs
            for (int c = 0; c < NC; ++c) {
                const int gbase = c * CHUNK;
                const int j1 = boff1[c];
                for (int j = boff0[c] + sub; j < j1; j += 8) {
                    const int wrd = binned[gbase + j];
                    const bool ok = ((wrd >> 17) == local);
                    const int s_ = ok ? (wrd & 0x1FFFF) : 0;
                    const float4 xns = *(const float4*)(xn + (size_t)s_ * HID + g * 4);
                    float p = xnt.x*xns.x + xnt.y*xns.y + xnt.z*xns.z + xnt.w*xns.w;
                    p += __shfl_xor(p, 1, 64); p += __shfl_xor(p, 2, 64); p += __shfl_xor(p, 4, 64);
                    const float wgt = ok ? __expf(beta * p) : 0.f;
                    const float f = wgt * sv[s_];
                    a0 += f*xns.x; a1 += f*xns.y; a2 += f*xns.z; a3 += f*xns.w;
                    dsum += wgt;
                }
            }
        }
        #pragma unroll
        for (int m = 8; m <= 32; m <<= 1) {
            a0 += __shfl_xor(a0, m, 64); a1 += __shfl_xor(a1, m, 64);
            a2 += __shfl_xor(a2, m, 64); a3 += __shfl_xor(a3, m, 64);
            dsum += __shfl_xor(dsum, m, 64);
        }
        // self-loop: x_i = sv[i] * xn_i
        const float wself = __expf(beta * sd);
        const float fs = wself * sv[node];
        a0 += fs*xnt.x; a1 += fs*xnt.y; a2 += fs*xnt.z; a3 += fs*xnt.w;
        dsum += wself;

        const float invd = 1.f / dsum;
        const float o0 = a0*invd, o1 = a1*invd, o2 = a2*invd, o3 = a3*invd;
        float l0 = o0*w0a + o1*w0b + o2*w0c + o3*w0d;
        float l1 = o0*w1a + o1*w1b + o2*w1c + o3*w1d;
        l0 += __shfl_xor(l0, 1, 64); l0 += __shfl_xor(l0, 2, 64); l0 += __shfl_xor(l0, 4, 64);
        l1 += __shfl_xor(l1, 1, 64); l1 += __shfl_xor(l1, 2, 64); l1 += __shfl_xor(l1, 4, 64);
        if (lane == 0) {
            l0 += bb0; l1 += bb1;
            float m = fmaxf(l0, l1);
            float lse = m + __logf(__expf(l0 - m) + __expf(l1 - m));
            out[2 * (size_t)node]     = l0 - lse;
            out[2 * (size_t)node + 1] = l1 - lse;
        }
    }
}

extern "C" void kernel_launch(void* const* d_in, const int* in_sizes, int n_in,
                              void* d_out, int out_size, void* d_ws, size_t ws_size,
                              hipStream_t stream) {
    const float* X    = (const float*)d_in[0];
    const float* w1   = (const float*)d_in[1];
    const float* b1   = (const float*)d_in[2];
    const float* beta = (const float*)d_in[3];
    const float* w2   = (const float*)d_in[4];
    const float* b2   = (const float*)d_in[5];
    const int*   ei   = (const int*)d_in[6];

    const int N = in_sizes[0] / NFEAT;       // 100000
    const int E = in_sizes[6] / 2;           // 1600000
    const int NB = (N + 63) >> 6;            // 1563 target buckets
    const int NC = (E + CHUNK - 1) / CHUNK;  // 391 chunks

    char* wsb = (char*)d_ws;
    float* xn     = (float*)wsb;  wsb += (size_t)N * HID * 4;          // 12.8 MB
    int*   binned = (int*)wsb;    wsb += (size_t)E * 4;                //  6.4 MB
    float* sv     = (float*)wsb;  wsb += (size_t)N * 4;
    int*   off2dT = (int*)wsb;    wsb += (size_t)(NB + 1) * NC * 4;    //  2.45 MB
    float* out    = (float*)d_out;

    k1_lin1_norm<<<(N + 7) / 8, 256, 0, stream>>>(X, w1, b1, xn, sv, N);
    kc_sort<<<NC, 256, 0, stream>>>(ei, binned, off2dT, E, NB, NC);
    k_fused<<<NB, 256, 0, stream>>>(binned, off2dT, xn, sv, beta, w2, b2, out, N, NB, NC);
}

// Round 6
// 219.987 us; speedup vs baseline: 3.9404x; 1.0312x over previous
//
#include <hip/hip_runtime.h>
#include <hip/hip_fp16.h>
#include <math.h>

#define HID 32
#define NFEAT 100
#define CHUNK 4096   // edges per chunk in kc_sort
#define NCMAX 512    // max chunks (E/CHUNK = 391)
#define NBMAX 2048   // max buckets (N/64 = 1563)
#define CAP 3072     // LDS edge capacity per bucket in k_fused (avg 1024, +64 sigma)

__device__ __forceinline__ float4 h4_to_f4(uint2 u) {
    __half2 a = *(__half2*)&u.x;
    __half2 b = *(__half2*)&u.y;
    float2 fa = __half22float2(a), fb = __half22float2(b);
    return make_float4(fa.x, fa.y, fb.x, fb.y);
}

// ---------------- K1: xh = fp16(relu(X@w1^T+b1)); invn = 1/max(||row||,1e-12) -------------
// 64 nodes/block; thread = (h 0..31, node-group 0..7); w transposed [k][h] in LDS.
__global__ __launch_bounds__(256) void k1_lin1_norm(
    const float* __restrict__ X, const float* __restrict__ w1,
    const float* __restrict__ b1,
    __half* __restrict__ xh, float* __restrict__ invn, int N)
{
    __shared__ float wT[NFEAT * 33];   // wT[k*33+h], conflict-free by h
    __shared__ float4 xs4[64 * 25];    // xs4[node*25 + kq]
    const int tid = threadIdx.x;
    const float4* w14 = (const float4*)w1;   // 32*100 floats = 800 float4 (100%4==0: row-safe)
    for (int i = tid; i < 800; i += 256) {
        float4 v = w14[i];
        int idx = i * 4, h = idx / NFEAT, k = idx % NFEAT;
        wT[k * 33 + h] = v.x; wT[(k + 1) * 33 + h] = v.y;
        wT[(k + 2) * 33 + h] = v.z; wT[(k + 3) * 33 + h] = v.w;
    }
    const int n0 = blockIdx.x * 64;
    const float4* X4 = (const float4*)X;     // row = 25 float4
    for (int i = tid; i < 1600; i += 256) {
        int r = i / 25, q = i % 25;
        int node = n0 + r;
        xs4[i] = (node < N) ? X4[(size_t)node * 25 + q] : make_float4(0.f, 0.f, 0.f, 0.f);
    }
    __syncthreads();

    const int h  = tid & 31;
    const int ng = tid >> 5;    // node group 0..7 (8 nodes each)
    const float bb = b1[h];
    float d[8] = {0.f, 0.f, 0.f, 0.f, 0.f, 0.f, 0.f, 0.f};

    #pragma unroll 5
    for (int kq = 0; kq < 25; ++kq) {
        const int kb = kq * 4;
        const float wa = wT[kb * 33 + h];
        const float wb = wT[(kb + 1) * 33 + h];
        const float wc = wT[(kb + 2) * 33 + h];
        const float wd = wT[(kb + 3) * 33 + h];
        #pragma unroll
        for (int j = 0; j < 8; ++j) {
            float4 xv = xs4[(ng * 8 + j) * 25 + kq];   // 2 distinct addrs/wave: broadcast
            d[j] = fmaf(xv.x, wa, d[j]);
            d[j] = fmaf(xv.y, wb, d[j]);
            d[j] = fmaf(xv.z, wc, d[j]);
            d[j] = fmaf(xv.w, wd, d[j]);
        }
    }
    #pragma unroll
    for (int j = 0; j < 8; ++j) {
        float v = fmaxf(d[j] + bb, 0.f);
        float s = v * v;
        #pragma unroll
        for (int m = 16; m >= 1; m >>= 1) s += __shfl_xor(s, m, 32);
        float inv = 1.f / fmaxf(sqrtf(s), 1e-12f);
        int node = n0 + ng * 8 + j;
        if (node < N) {
            xh[(size_t)node * HID + h] = __float2half(v);
            if (h == 0) invn[node] = inv;
        }
    }
}

// ---------------- Chunk-local bucket sort; offsets written coalesced as u16 [c][NB+1] -------
__global__ __launch_bounds__(256) void kc_sort(
    const int* __restrict__ ei, int* __restrict__ binned,
    unsigned short* __restrict__ offU, int E, int NB, int NC)
{
    __shared__ int hist[NBMAX];
    __shared__ int off[NBMAX];
    const int tid = threadIdx.x;
    const int c = blockIdx.x;
    const int start = c * CHUNK;
    const int end = min(start + CHUNK, E);
    for (int b = tid; b < NB; b += 256) hist[b] = 0;
    __syncthreads();
    for (int e = start + tid; e < end; e += 256)
        atomicAdd(&hist[ei[E + e] >> 6], 1);
    __syncthreads();
    if (tid < 64) {   // wave 0: exclusive scan, 64 buckets/round with carry
        int carry = 0;
        for (int r = 0; r * 64 < NB; ++r) {
            int b = r * 64 + tid;
            int v = (b < NB) ? hist[b] : 0;
            int x = v;
            #pragma unroll
            for (int dd = 1; dd < 64; dd <<= 1) {
                int y = __shfl_up(x, dd, 64);
                if (tid >= dd) x += y;
            }
            if (b < NB) off[b] = carry + x - v;
            carry += __shfl(x, 63, 64);
        }
    }
    __syncthreads();
    const size_t urow = (size_t)c * (NB + 1);
    for (int b = tid; b < NB; b += 256) {
        offU[urow + b] = (unsigned short)off[b];   // coalesced u16 writes
        hist[b] = off[b];                           // reuse as local cursor
    }
    if (tid == 0) offU[urow + NB] = (unsigned short)(end - start);
    __syncthreads();
    for (int e = start + tid; e < end; e += 256) {
        int t = ei[E + e];
        int b = t >> 6;
        int pos = atomicAdd(&hist[b], 1);
        binned[start + pos] = ei[e] | ((t & 63) << 17);  // src<2^17, local 6 bits
    }
}

// ---------------- Transpose offU [C][R] u16 -> offT [R][C] (R=NB+1, C=NC) ----------------
__global__ __launch_bounds__(256) void k_transpose(
    const unsigned short* __restrict__ in, unsigned short* __restrict__ outp, int R, int C)
{
    __shared__ unsigned short tile[64][65];
    const int b0 = blockIdx.x * 64, c0 = blockIdx.y * 64;
    const int tx = threadIdx.x & 63, ty0 = threadIdx.x >> 6;
    for (int ty = ty0; ty < 64; ty += 4) {
        int c = c0 + ty, b = b0 + tx;
        tile[ty][tx] = (c < C && b < R) ? in[(size_t)c * R + b] : 0;
    }
    __syncthreads();
    for (int ty = ty0; ty < 64; ty += 4) {
        int b = b0 + ty, c = c0 + tx;
        if (b < R && c < C) outp[(size_t)b * C + c] = tile[tx][ty];
    }
}

// ---------------- Fused: sub-runs -> LDS sort -> fp16 gather + lin2 + log_softmax ----------
__global__ __launch_bounds__(256) void k_fused(
    const int* __restrict__ binned, const unsigned short* __restrict__ offT,
    const __half* __restrict__ xh, const float* __restrict__ invn,
    const float* __restrict__ pbeta,
    const float* __restrict__ w2, const float* __restrict__ b2,
    float* __restrict__ out, int N, int NB, int NC)
{
    __shared__ unsigned short b0s[NCMAX], b1s[NCMAX];
    __shared__ int cnt[64], cur[64];
    __shared__ int led[CAP];
    __shared__ int ovf;
    const int tid  = threadIdx.x;
    const int lane = tid & 63;
    const int wv   = tid >> 6;
    const int g    = lane & 7;   // feature slice: halfs g*4 .. g*4+3
    const int sub  = lane >> 3;  // edge slot 0..7
    const int b    = blockIdx.x;
    const float beta = *pbeta;
    const float w0a = w2[g*4], w0b = w2[g*4+1], w0c = w2[g*4+2], w0d = w2[g*4+3];
    const float w1a = w2[HID+g*4], w1b = w2[HID+g*4+1], w1c = w2[HID+g*4+2], w1d = w2[HID+g*4+3];
    const float bb0 = b2[0], bb1 = b2[1];

    for (int c = tid; c < NC; c += 256) {
        b0s[c] = offT[(size_t)b * NC + c];
        b1s[c] = offT[(size_t)(b + 1) * NC + c];
    }
    if (tid < 64) cnt[tid] = 0;
    if (tid == 0) ovf = 0;
    __syncthreads();
    // pass A: per-node degree counts from global sub-runs
    for (int c = tid; c < NC; c += 256) {
        const int gbase = c * CHUNK;
        const int j1 = b1s[c];
        for (int j = b0s[c]; j < j1; ++j)
            atomicAdd(&cnt[binned[gbase + j] >> 17], 1);
    }
    __syncthreads();
    if (tid < 64) {
        int v = cnt[tid], x = v;
        #pragma unroll
        for (int dd = 1; dd < 64; dd <<= 1) {
            int y = __shfl_up(x, dd, 64);
            if (tid >= dd) x += y;
        }
        cur[tid] = x - v;
        if (tid == 63 && x > CAP) ovf = 1;
    }
    __syncthreads();
    const bool fits = (ovf == 0);
    if (fits) {   // pass B: scatter src ids into LDS grouped by local node (L2-hot re-read)
        for (int c = tid; c < NC; c += 256) {
            const int gbase = c * CHUNK;
            const int j1 = b1s[c];
            for (int j = b0s[c]; j < j1; ++j) {
                int w = binned[gbase + j];
                int pos = atomicAdd(&cur[w >> 17], 1);
                led[pos] = w & 0x1FFFF;
            }
        }
    }
    __syncthreads();

    for (int local = wv; local < 64; local += 4) {
        const int node = b * 64 + local;
        if (node >= N) break;   // monotone -> uniform break per wave

        const float ivt = invn[node];
        const uint2 ut = *(const uint2*)(xh + (size_t)node * HID + g * 4);
        const float4 xt = h4_to_f4(ut);
        float sd = xt.x*xt.x + xt.y*xt.y + xt.z*xt.z + xt.w*xt.w;
        sd += __shfl_xor(sd, 1, 64); sd += __shfl_xor(sd, 2, 64); sd += __shfl_xor(sd, 4, 64);

        float a0 = 0.f, a1 = 0.f, a2 = 0.f, a3 = 0.f, dsum = 0.f;
        const int deg = cnt[local];

        if (fits) {
            const int st = cur[local] - deg;   // cur ended at start+deg
            for (int e0 = 0; e0 < deg; e0 += 8) {
                const int e = e0 + sub;        // uniform within 8-lane group
                if (e < deg) {
                    const int s_ = led[st + e];
                    const uint2 us = *(const uint2*)(xh + (size_t)s_ * HID + g * 4);
                    const float4 xs = h4_to_f4(us);
                    float p = xt.x*xs.x + xt.y*xs.y + xt.z*xs.z + xt.w*xs.w;
                    p += __shfl_xor(p, 1, 64); p += __shfl_xor(p, 2, 64); p += __shfl_xor(p, 4, 64);
                    const float ivs = invn[s_];
                    const float wgt = __expf(beta * p * ivt * ivs);   // cos in [-1,1]: exp safe
                    a0 += wgt*xs.x; a1 += wgt*xs.y; a2 += wgt*xs.z; a3 += wgt*xs.w;
                    dsum += wgt;
                }
            }
        } else {
            // fallback (bucket > CAP, practically never): filter all sub-runs from global
            for (int c = 0; c < NC; ++c) {
                const int gbase = c * CHUNK;
                const int j1 = b1s[c];
                for (int j = b0s[c] + sub; j < j1; j += 8) {
                    const int wrd = binned[gbase + j];
                    const bool ok = ((wrd >> 17) == local);
                    const int s_ = ok ? (wrd & 0x1FFFF) : 0;
                    const uint2 us = *(const uint2*)(xh + (size_t)s_ * HID + g * 4);
                    const float4 xs = h4_to_f4(us);
                    float p = xt.x*xs.x + xt.y*xs.y + xt.z*xs.z + xt.w*xs.w;
                    p += __shfl_xor(p, 1, 64); p += __shfl_xor(p, 2, 64); p += __shfl_xor(p, 4, 64);
                    const float ivs = invn[s_];
                    const float wgt = ok ? __expf(beta * p * ivt * ivs) : 0.f;
                    a0 += wgt*xs.x; a1 += wgt*xs.y; a2 += wgt*xs.z; a3 += wgt*xs.w;
                    dsum += wgt;
                }
            }
        }
        #pragma unroll
        for (int m = 8; m <= 32; m <<= 1) {
            a0 += __shfl_xor(a0, m, 64); a1 += __shfl_xor(a1, m, 64);
            a2 += __shfl_xor(a2, m, 64); a3 += __shfl_xor(a3, m, 64);
            dsum += __shfl_xor(dsum, m, 64);
        }
        // self-loop (same fp16 row for consistency)
        const float wself = __expf(beta * sd * ivt * ivt);
        a0 += wself*xt.x; a1 += wself*xt.y; a2 += wself*xt.z; a3 += wself*xt.w;
        dsum += wself;

        const float invd = 1.f / dsum;
        const float o0 = a0*invd, o1 = a1*invd, o2 = a2*invd, o3 = a3*invd;
        float l0 = o0*w0a + o1*w0b + o2*w0c + o3*w0d;
        float l1 = o0*w1a + o1*w1b + o2*w1c + o3*w1d;
        l0 += __shfl_xor(l0, 1, 64); l0 += __shfl_xor(l0, 2, 64); l0 += __shfl_xor(l0, 4, 64);
        l1 += __shfl_xor(l1, 1, 64); l1 += __shfl_xor(l1, 2, 64); l1 += __shfl_xor(l1, 4, 64);
        if (lane == 0) {
            l0 += bb0; l1 += bb1;
            float m = fmaxf(l0, l1);
            float lse = m + __logf(__expf(l0 - m) + __expf(l1 - m));
            out[2 * (size_t)node]     = l0 - lse;
            out[2 * (size_t)node + 1] = l1 - lse;
        }
    }
}

extern "C" void kernel_launch(void* const* d_in, const int* in_sizes, int n_in,
                              void* d_out, int out_size, void* d_ws, size_t ws_size,
                              hipStream_t stream) {
    const float* X    = (const float*)d_in[0];
    const float* w1   = (const float*)d_in[1];
    const float* b1   = (const float*)d_in[2];
    const float* beta = (const float*)d_in[3];
    const float* w2   = (const float*)d_in[4];
    const float* b2   = (const float*)d_in[5];
    const int*   ei   = (const int*)d_in[6];

    const int N = in_sizes[0] / NFEAT;       // 100000
    const int E = in_sizes[6] / 2;           // 1600000
    const int NB = (N + 63) >> 6;            // 1563 target buckets
    const int NC = (E + CHUNK - 1) / CHUNK;  // 391 chunks
    const int R  = NB + 1;                   // offset-table rows

    char* wsb = (char*)d_ws;
    __half* xhp  = (__half*)wsb;          wsb += (size_t)N * HID * 2;   // 6.4 MB
    float* invn  = (float*)wsb;           wsb += (size_t)N * 4;
    int*   binned = (int*)wsb;            wsb += (size_t)E * 4;         // 6.4 MB
    unsigned short* offU = (unsigned short*)wsb; wsb += (size_t)R * NC * 2;
    unsigned short* offT = (unsigned short*)wsb; wsb += (size_t)R * NC * 2;
    float* out   = (float*)d_out;

    k1_lin1_norm<<<(N + 63) / 64, 256, 0, stream>>>(X, w1, b1, xhp, invn, N);
    kc_sort<<<NC, 256, 0, stream>>>(ei, binned, offU, E, NB, NC);
    k_transpose<<<dim3((R + 63) / 64, (NC + 63) / 64), 256, 0, stream>>>(offU, offT, R, NC);
    k_fused<<<NB, 256, 0, stream>>>(binned, offT, xhp, invn, beta, w2, b2, out, N, NB, NC);
}